// Round 11
// baseline (25303.156 us; speedup 1.0000x reference)
//
#include <hip/hip_runtime.h>
#include <cstddef>
#include <cstdint>
#include <math.h>

// B=64, T=512, V=50002, E=300, H=256, K=11, START=9, STOP=10
// Output: [64 score][64*512 path] floats = 32832.
// Session laws: ws in [22,479,872+, 24.0e6) B. Coop grids must be <=32 blocks
// (64-block grids step ~4x slower - R9/R10). 256-thread coop kernels never run;
// 512-thread ones do. Coop fixed cost ~15us/launch. h0-as-bf16 validated (R10, absmax 0).
// Fused-gather + direct-B GEMM validated (R9, absmax 0).

__device__ __forceinline__ float sigmf_(float x){ return 1.0f/(1.0f+expf(-x)); }
__device__ __forceinline__ unsigned short f2bf(float x){
  union{float f;unsigned u;} v; v.f = x;
  unsigned r = v.u + 0x7FFF + ((v.u>>16)&1);
  return (unsigned short)(r>>16);
}
__device__ __forceinline__ float bf2f(unsigned short b){
  union{float f;unsigned u;} v; v.u = ((unsigned)b)<<16; return v.f;
}

// ---------------- generic zero ----------------
__global__ void k_zero(float* __restrict__ p, int n){
  for (int i = blockIdx.x*blockDim.x + threadIdx.x; i < n; i += gridDim.x*blockDim.x) p[i] = 0.f;
}

// ------- dual GEMM (z=0/1): xw[M,1024] = A @ B^T + bias (R9+R10 validated paths merged) -------
// embMode=1: A rows = emb[sent[...]] fp32 (fused gather, kmax guard).
// embMode=0: A = strided rows; aBf16 selects ushort(bf16) vs float elements.
// B = raw w_ih [1024, ldb] row-major, loaded transposed with k<kmax guard (L2-resident).
__global__ __launch_bounds__(256) void k_gemm2e(
    const float* __restrict__ A0, const float* __restrict__ A1, int lda, int kTiles, int kmax,
    int aBf16, int aBstride, int sOff0, int sOff1, int logT, int Tm1,
    const int* __restrict__ sent, const float* __restrict__ emb, int b0, int embMode,
    const float* __restrict__ B0, const float* __restrict__ B1, int ldb,
    const float* __restrict__ bias0, const float* __restrict__ bias1,
    float* __restrict__ C0, float* __restrict__ C1){
  __shared__ float As[16][132];
  __shared__ float Bs[16][132];
  const int z = blockIdx.z;
  const float* A   = z ? A1 : A0;
  const float* Bm  = z ? B1 : B0;
  const float* bias= z ? bias1 : bias0;
  float* Cc        = z ? C1 : C0;
  const int sOff   = z ? sOff1 : sOff0;
  const int t  = threadIdx.x;
  const int tx = t & 15, ty = t >> 4;
  const int m0 = blockIdx.y * 128, n0 = blockIdx.x * 128;
  const int arow = t >> 2, ak = (t & 3) * 4;
  const int brow = t >> 5, bc = (t & 31) * 4;
  const int gm0 = m0 + arow, gm1 = m0 + arow + 64;
  const float* rp0; const float* rp1;
  const unsigned short* rb0 = nullptr; const unsigned short* rb1 = nullptr;
  if (embMode){
    int tok0 = sent[(size_t)(b0 + (gm0 >> logT))*512 + sOff + (gm0 & Tm1)];
    int tok1 = sent[(size_t)(b0 + (gm1 >> logT))*512 + sOff + (gm1 & Tm1)];
    rp0 = emb + (size_t)tok0*300;
    rp1 = emb + (size_t)tok1*300;
  } else {
    const size_t r0 = (size_t)(gm0 >> logT)*aBstride + sOff + (gm0 & Tm1);
    const size_t r1 = (size_t)(gm1 >> logT)*aBstride + sOff + (gm1 & Tm1);
    rp0 = A + r0*lda;
    rp1 = A + r1*lda;
    rb0 = ((const unsigned short*)A) + r0*lda;
    rb1 = ((const unsigned short*)A) + r1*lda;
  }
  float acc[8][8] = {};
  for (int kt = 0; kt < kTiles; ++kt){
    const int kb = kt * 16;
    float4 a0 = make_float4(0.f,0.f,0.f,0.f), a1 = a0;
    if (kb + ak < kmax){
      if (aBf16){
        ushort4 u0 = *(const ushort4*)(rb0 + kb + ak);
        ushort4 u1 = *(const ushort4*)(rb1 + kb + ak);
        a0 = make_float4(bf2f(u0.x), bf2f(u0.y), bf2f(u0.z), bf2f(u0.w));
        a1 = make_float4(bf2f(u1.x), bf2f(u1.y), bf2f(u1.z), bf2f(u1.w));
      } else {
        a0 = *(const float4*)(rp0 + kb + ak);
        a1 = *(const float4*)(rp1 + kb + ak);
      }
    }
    float bv0[4], bv1[4];
    {
      const int k0 = kb + brow, k1 = kb + brow + 8;
      #pragma unroll
      for (int i = 0; i < 4; ++i){
        const size_t n = (size_t)(n0 + bc + i);
        bv0[i] = (k0 < kmax) ? Bm[n*ldb + k0] : 0.f;
        bv1[i] = (k1 < kmax) ? Bm[n*ldb + k1] : 0.f;
      }
    }
    __syncthreads();
    As[ak+0][arow] = a0.x; As[ak+1][arow] = a0.y; As[ak+2][arow] = a0.z; As[ak+3][arow] = a0.w;
    As[ak+0][arow+64] = a1.x; As[ak+1][arow+64] = a1.y; As[ak+2][arow+64] = a1.z; As[ak+3][arow+64] = a1.w;
    Bs[brow  ][bc+0] = bv0[0]; Bs[brow  ][bc+1] = bv0[1]; Bs[brow  ][bc+2] = bv0[2]; Bs[brow  ][bc+3] = bv0[3];
    Bs[brow+8][bc+0] = bv1[0]; Bs[brow+8][bc+1] = bv1[1]; Bs[brow+8][bc+2] = bv1[2]; Bs[brow+8][bc+3] = bv1[3];
    __syncthreads();
    #pragma unroll
    for (int k = 0; k < 16; ++k){
      float av[8], bv[8];
      *(float4*)&av[0] = *(const float4*)&As[k][ty*8];
      *(float4*)&av[4] = *(const float4*)&As[k][ty*8+4];
      *(float4*)&bv[0] = *(const float4*)&Bs[k][tx*8];
      *(float4*)&bv[4] = *(const float4*)&Bs[k][tx*8+4];
      #pragma unroll
      for (int i = 0; i < 8; ++i)
        #pragma unroll
        for (int jj = 0; jj < 8; ++jj)
          acc[i][jj] = fmaf(av[i], bv[jj], acc[i][jj]);
    }
  }
  float bvals[8];
  #pragma unroll
  for (int e = 0; e < 8; ++e) bvals[e] = bias[n0 + tx*8 + e];
  float* Cp = Cc + (size_t)(m0 + ty*8)*1024 + n0 + tx*8;
  #pragma unroll
  for (int i = 0; i < 8; ++i){
    float4 o0 = make_float4(acc[i][0]+bvals[0], acc[i][1]+bvals[1], acc[i][2]+bvals[2], acc[i][3]+bvals[3]);
    float4 o1 = make_float4(acc[i][4]+bvals[4], acc[i][5]+bvals[5], acc[i][6]+bvals[6], acc[i][7]+bvals[7]);
    *(float4*)(Cp + (size_t)i*1024)     = o0;
    *(float4*)(Cp + (size_t)i*1024 + 4) = o1;
  }
}

// ---------------- LSTM recurrence: R8 skeleton, TWO batches per block ----------------
// Block = (superchain sc, hh): sc = u*2+dir covers batches {2u, 2u+1} of direction dir.
// Same W per block as R8 (24 float4-pairs VGPR + 8-pair LDS tail); per thread computes
// the two batches' dots with shared weights (2x FMA, same handshake). Grid = 2*C <= 32.
// Per-batch FMA order identical to R8 -> fp32-exact. Pairwise flag protocol (R8-proven).
__global__ __launch_bounds__(512, 2) void k_lstm2d(
    const float* __restrict__ xwF, const float* __restrict__ xwB,
    const float* __restrict__ whhf, const float* __restrict__ whhb,
    float* __restrict__ hout, int hBstride, int tOffF, int tOffB,
    int T, int epoch, int bf16out,
    float* __restrict__ hx, int* __restrict__ flags,
    float* __restrict__ hsave, float* __restrict__ csave)
{
  __shared__ float hfA[256], hfB[256];
  __shared__ float glsA[512], glsB[512];
  __shared__ float wtail[512*66];       // 135 KB
  const int blk = blockIdx.x;
  const int sc = blk >> 1;              // superchain = u*2 + dir
  const int hh = blk & 1;
  const int u = sc >> 1;
  const int dir = sc & 1;
  const int bA = u*2, bB = u*2 + 1;     // two local batches, same dir
  const int t = threadIdx.x;
  const int wv = t >> 6, lane = t & 63;
  const int kap = lane >> 5, li = lane & 31;
  const int r0 = wv*64 + li*2;
  const int rK = r0 + kap;
  const int gateK = rK >> 7;
  float4 w0[24], w1[24];
  {
    const float* whh = dir ? whhb : whhf;
    const int g0 = r0 >> 7, i0 = r0 & 127;
    const float* a = whh + (size_t)(g0*256 + hh*128 + i0)*256 + kap*128;
    const float* b = a + 256;
    #pragma unroll
    for (int q = 0; q < 24; ++q){ w0[q] = *(const float4*)(a + q*4); w1[q] = *(const float4*)(b + q*4); }
    for (int q = 24; q < 32; ++q){
      #pragma unroll
      for (int e = 0; e < 4; ++e){
        wtail[t*66 + (q-24)*4 + e]      = a[q*4 + e];
        wtail[t*66 + 32 + (q-24)*4 + e] = b[q*4 + e];
      }
    }
  }
  const int chA = bA*2 + dir, chB = bB*2 + dir;
  if (t < 256){ hfA[t] = hsave[chA*256 + t]; hfB[t] = hsave[chB*256 + t]; }
  float cA = (t < 128) ? csave[chA*256 + hh*128 + t] : 0.f;
  float cB = (t < 128) ? csave[chB*256 + hh*128 + t] : 0.f;
  __syncthreads();
  const int xcol = gateK*256 + hh*128 + (rK & 127);
  const float* xwp = dir ? xwB : xwF;
  const float* xbA = xwp + (size_t)bA*T*1024 + xcol;
  const float* xbB = xwp + (size_t)bB*T*1024 + xcol;
  float* hxme       = hx + (size_t)(sc*2 + hh)*512;       // [parity][2 batches][128]
  const float* hxpt = hx + (size_t)(sc*2 + (1-hh))*512;
  int* flg  = flags + sc*2 + hh;
  int* flgp = flags + sc*2 + (1-hh);
  const int tOff = dir ? tOffB : tOffF;
  const size_t hobA = (size_t)bA*hBstride + dir*256 + hh*128;
  const size_t hobB = (size_t)bB*hBstride + dir*256 + hh*128;
  const float* wtb = &wtail[t*66];
  float xgA = xbA[(size_t)(dir ? (T-1) : 0)*1024];
  float xgB = xbB[(size_t)(dir ? (T-1) : 0)*1024];
  for (int s = 0; s < T; ++s){
    const int tt = dir ? (T-1-s) : s;
    float xnA = 0.f, xnB = 0.f;
    if (s < T-1){
      const size_t tn = (size_t)(dir ? (T-2-s) : (s+1))*1024;
      xnA = xbA[tn]; xnB = xbB[tn];           // prefetch both batches
    }
    float p0A = 0.f, p1A = 0.f, p0B = 0.f, p1B = 0.f;
    const float4* h4A = ((const float4*)hfA) + kap*32;
    const float4* h4B = ((const float4*)hfB) + kap*32;
    #pragma unroll
    for (int q = 0; q < 24; ++q){
      float4 a4 = h4A[q], b4 = h4B[q];        // 2-way LDS broadcast (free)
      p0A = fmaf(w0[q].x, a4.x, p0A);  p1A = fmaf(w1[q].x, a4.x, p1A);
      p0B = fmaf(w0[q].x, b4.x, p0B);  p1B = fmaf(w1[q].x, b4.x, p1B);
      p0A = fmaf(w0[q].y, a4.y, p0A);  p1A = fmaf(w1[q].y, a4.y, p1A);
      p0B = fmaf(w0[q].y, b4.y, p0B);  p1B = fmaf(w1[q].y, b4.y, p1B);
      p0A = fmaf(w0[q].z, a4.z, p0A);  p1A = fmaf(w1[q].z, a4.z, p1A);
      p0B = fmaf(w0[q].z, b4.z, p0B);  p1B = fmaf(w1[q].z, b4.z, p1B);
      p0A = fmaf(w0[q].w, a4.w, p0A);  p1A = fmaf(w1[q].w, a4.w, p1A);
      p0B = fmaf(w0[q].w, b4.w, p0B);  p1B = fmaf(w1[q].w, b4.w, p1B);
    }
    #pragma unroll
    for (int q = 24; q < 32; ++q){            // LDS W tail: read once, use for both batches
      float4 a4 = h4A[q], b4 = h4B[q];
      const int o = (q-24)*4;
      float u0 = wtb[o+0], u1 = wtb[o+1], u2 = wtb[o+2], u3 = wtb[o+3];
      float v0 = wtb[32+o+0], v1 = wtb[32+o+1], v2 = wtb[32+o+2], v3 = wtb[32+o+3];
      p0A = fmaf(u0, a4.x, p0A);  p1A = fmaf(v0, a4.x, p1A);
      p0B = fmaf(u0, b4.x, p0B);  p1B = fmaf(v0, b4.x, p1B);
      p0A = fmaf(u1, a4.y, p0A);  p1A = fmaf(v1, a4.y, p1A);
      p0B = fmaf(u1, b4.y, p0B);  p1B = fmaf(v1, b4.y, p1B);
      p0A = fmaf(u2, a4.z, p0A);  p1A = fmaf(v2, a4.z, p1A);
      p0B = fmaf(u2, b4.z, p0B);  p1B = fmaf(v2, b4.z, p1B);
      p0A = fmaf(u3, a4.w, p0A);  p1A = fmaf(v3, a4.w, p1A);
      p0B = fmaf(u3, b4.w, p0B);  p1B = fmaf(v3, b4.w, p1B);
    }
    float q0A = p0A + __shfl_xor(p0A, 32, 64);
    float q1A = p1A + __shfl_xor(p1A, 32, 64);
    float q0B = p0B + __shfl_xor(p0B, 32, 64);
    float q1B = p1B + __shfl_xor(p1B, 32, 64);
    float accA = (kap ? q1A : q0A) + xgA;
    float accB = (kap ? q1B : q0B) + xgB;
    float actA = (gateK == 2) ? tanhf(accA) : sigmf_(accA);
    float actB = (gateK == 2) ? tanhf(accB) : sigmf_(accB);
    glsA[rK] = actA; glsB[rK] = actB;
    __syncthreads();                          // B1: gates ready
    if (t < 128){
      cA = glsA[128+t]*cA + glsA[t]*glsA[256+t];
      float hA = glsA[384+t]*tanhf(cA);
      cB = glsB[128+t]*cB + glsB[t]*glsB[256+t];
      float hB = glsB[384+t]*tanhf(cB);
      hfA[hh*128 + t] = hA;  hfB[hh*128 + t] = hB;
      hxme[(s&1)*256 + t] = hA;  hxme[(s&1)*256 + 128 + t] = hB;
      size_t oA = hobA + (size_t)(tOff + tt)*512 + t;
      size_t oB = hobB + (size_t)(tOff + tt)*512 + t;
      if (bf16out){ ((unsigned short*)hout)[oA] = f2bf(hA); ((unsigned short*)hout)[oB] = f2bf(hB); }
      else { hout[oA] = hA; hout[oB] = hB; }
    }
    __syncthreads();                          // B2: stores drained
    if (t == 0){
      __hip_atomic_store(flg, epoch + s + 1, __ATOMIC_RELEASE, __HIP_MEMORY_SCOPE_AGENT);
      int lim = 0;                            // bounded spin (hang fuse)
      while (__hip_atomic_load(flgp, __ATOMIC_ACQUIRE, __HIP_MEMORY_SCOPE_AGENT) < epoch + s + 1
             && ++lim < (1<<20)) {}
    }
    __syncthreads();                          // B3: partner data visible
    if (t < 128){
      hfA[(1-hh)*128 + t] = hxpt[(s&1)*256 + t];
      hfB[(1-hh)*128 + t] = hxpt[(s&1)*256 + 128 + t];
    }
    __syncthreads();                          // B4: ready for next step
    xgA = xnA; xgB = xnB;
  }
  if (t < 128){
    hsave[chA*256 + hh*128 + t] = hfA[hh*128 + t];
    hsave[chB*256 + hh*128 + t] = hfB[hh*128 + t];
    csave[chA*256 + hh*128 + t] = cA;
    csave[chB*256 + hh*128 + t] = cB;
  }
}

// ---------------- feats accumulation (one dir half per call; R5/R8/R9-proven) ----------------
__global__ __launch_bounds__(256) void k_feats_half(
    const float* __restrict__ h1s, const float* __restrict__ fcw, const float* __restrict__ fcb,
    float* __restrict__ feats, int b0, int logT, int Tm1, int tG0, int dir){
  int wv = threadIdx.x >> 6, lane = threadIdx.x & 63;
  int m = blockIdx.x*4 + wv;                 // m = bl*T + tl
  const float4* row = (const float4*)(h1s + (size_t)m*512 + dir*256);
  float4 rv = row[lane];
  int bl = m >> logT, tl = m & Tm1;
  size_t fbase = ((size_t)(b0 + bl)*512 + tG0 + tl)*11;
  #pragma unroll
  for (int n = 0; n < 11; ++n){
    const float4* wr = (const float4*)(fcw + n*512 + dir*256);
    float4 w4 = wr[lane];
    float p = rv.x*w4.x + rv.y*w4.y + rv.z*w4.z + rv.w*w4.w;
    #pragma unroll
    for (int off = 32; off > 0; off >>= 1) p += __shfl_down(p, off, 64);
    if (lane == 0){
      float add = (dir == 0) ? (p + fcb[n]) : p;
      feats[fbase + n] += add;
    }
  }
}

// ---------------- Viterbi: 1 wave per batch (R2/R5/R8-proven) ----------------
__global__ __launch_bounds__(256) void k_viterbi(const float* __restrict__ feats,
                        const float* __restrict__ trans, float* __restrict__ out){
  __shared__ unsigned char bp[4][512][12];
  const int wave = threadIdx.x >> 6, lane = threadIdx.x & 63;
  const int b = blockIdx.x*4 + wave;
  const int j = lane;
  float tr[11];
  float fv;
  if (j < 11){
    #pragma unroll
    for (int p = 0; p < 11; ++p) tr[p] = trans[j*11 + p];
    fv = (j == 9) ? 0.f : -1000.f;
  } else {
    #pragma unroll
    for (int p = 0; p < 11; ++p) tr[p] = -1e30f;
    fv = -1e30f;
  }
  for (int t = 0; t < 512; ++t){
    float best = -1e38f; int bestp = 0;
    #pragma unroll
    for (int p = 0; p < 11; ++p){
      float v = __shfl(fv, p, 64) + tr[p];
      if (v > best){ best = v; bestp = p; }   // strict > keeps FIRST max (np.argmax)
    }
    float feat = (j < 11) ? feats[((size_t)b*512 + t)*11 + j] : 0.f;
    fv = best + feat;
    if (j < 11) bp[wave][t][j] = (unsigned char)bestp;
  }
  float term = (j < 11) ? fv + trans[10*11 + j] : -1e38f;
  float best = -1e38f; int bestp = 0;
  #pragma unroll
  for (int p = 0; p < 11; ++p){
    float v = __shfl(term, p, 64);
    if (v > best){ best = v; bestp = p; }
  }
  if (lane == 0){
    out[b] = best;
    float* path = out + 64 + (size_t)b*512;
    int cur = bestp;
    path[511] = (float)cur;
    for (int t = 511; t >= 1; --t){
      cur = bp[wave][t][cur];
      path[t-1] = (float)cur;
    }
  }
}

extern "C" void kernel_launch(void* const* d_in, const int* in_sizes, int n_in,
                              void* d_out, int out_size, void* d_ws, size_t ws_size,
                              hipStream_t stream){
  const int*   sent  = (const int*)d_in[0];
  const float* emb   = (const float*)d_in[2];
  const float* fcw   = (const float*)d_in[3];
  const float* fcb   = (const float*)d_in[4];
  const float* trans = (const float*)d_in[5];
  const float* wih0f = (const float*)d_in[6];
  const float* whh0f = (const float*)d_in[7];
  const float* b0f   = (const float*)d_in[8];
  const float* wih0b = (const float*)d_in[9];
  const float* whh0b = (const float*)d_in[10];
  const float* b0b   = (const float*)d_in[11];
  const float* wih1f = (const float*)d_in[12];
  const float* whh1f = (const float*)d_in[13];
  const float* b1f   = (const float*)d_in[14];
  const float* wih1b = (const float*)d_in[15];
  const float* whh1b = (const float*)d_in[16];
  const float* b1b   = (const float*)d_in[17];

  float* ws = (float*)d_ws;
  // -------- fixed region (R9 layout: no wT, no X) --------
  const size_t o_hx   = 0;                       // sc*2+hh slots * 512 <= 65536
  const size_t o_flag = o_hx   + 65536;          // 256 ints
  const size_t o_hs   = o_flag + 256;            // hsave 128 chains * 256 = 32768
  const size_t o_cs   = o_hs   + 32768;          // csave 32768
  const size_t o_feat = o_cs   + 32768;          // 32768*11 = 360448
  const size_t o_var  = o_feat + 360448;         // = 491,776 floats fixed (1.97 MB)
  float* hx    = ws + o_hx;
  int*   flags = (int*)(ws + o_flag);
  float* hsave = ws + o_hs;
  float* csave = ws + o_cs;
  float* feats = ws + o_feat;

  // -------- adaptive (C,T): need = o_var + 2CT*1024 (xw) + C*131072 (h0 bf16) + CT*512 (h1s)
  // (16,64) = 20,841,472 B < 22,479,872 proven -> guaranteed selection. C even (batch pairs).
  int C = 8, T = 32, logT = 5;
  {
    const int cc[4]  = {16, 8, 8, 4};
    const int tt[4]  = {64, 64, 32, 64};
    const int lt[4]  = { 6,  6,  5,  6};
    for (int i = 0; i < 4; ++i){
      size_t need = (o_var + (size_t)2*cc[i]*tt[i]*1024 + (size_t)cc[i]*131072
                     + (size_t)cc[i]*tt[i]*512)*4;
      if (need <= ws_size){ C = cc[i]; T = tt[i]; logT = lt[i]; break; }
    }
  }
  const int Tm1 = T - 1, S = 512 / T;
  float* xwF = ws + o_var;                        // [C*T,1024] fp32
  float* xwB = xwF + (size_t)C*T*1024;
  float* h0  = xwB + (size_t)C*T*1024;            // [C,512,512] bf16 (C*131072 float-equiv)
  float* h1s = h0  + (size_t)C*131072;            // [C,T,512] fp32

  hipLaunchKernelGGL(k_zero, dim3(512), dim3(256), 0, stream, feats, 360448);

  for (int b0 = 0; b0 < 64; b0 += C){
    for (int layer = 0; layer < 2; ++layer){
      // zero hx + flags + hsave + csave (contiguous)
      hipLaunchKernelGGL(k_zero, dim3(256), dim3(256), 0, stream, ws + o_hx, 65536 + 256 + 65536);
      const float* whF = layer ? whh1f : whh0f;
      const float* whB = layer ? whh1b : whh0b;
      for (int sl = 0; sl < S; ++sl){
        const int sF = sl, sB = S - 1 - sl;
        const int M = C*T;
        if (layer == 0){
          hipLaunchKernelGGL(k_gemm2e, dim3(8, M/128, 2), dim3(256), 0, stream,
                             (const float*)nullptr, (const float*)nullptr, 0, 19, 300,
                             0, 0, sF*T, sB*T, logT, Tm1,
                             sent, emb, b0, 1,
                             wih0f, wih0b, 300, b0f, b0b, xwF, xwB);
        } else {
          hipLaunchKernelGGL(k_gemm2e, dim3(8, M/128, 2), dim3(256), 0, stream,
                             h0, h0, 512, 32, 512,
                             1, 512, sF*T, sB*T, logT, Tm1,
                             sent, emb, b0, 0,
                             wih1f, wih1b, 512, b1f, b1b, xwF, xwB);
        }
        {
          const float *xF = xwF, *xB = xwB, *wF = whF, *wB = whB;
          float* hop = layer ? h1s : h0;
          int hBs  = layer ? T*512 : 512*512;     // element stride per batch
          int tOF  = layer ? 0 : sF*T;
          int tOB  = layer ? 0 : sB*T;
          int Tk = T, ep = sl*T, bfo = layer ? 0 : 1;
          float *hxp = hx, *hsp = hsave, *csp = csave; int *flp = flags;
          void* args[] = {(void*)&xF, (void*)&xB, (void*)&wF, (void*)&wB,
                          (void*)&hop, (void*)&hBs, (void*)&tOF, (void*)&tOB,
                          (void*)&Tk, (void*)&ep, (void*)&bfo,
                          (void*)&hxp, (void*)&flp, (void*)&hsp, (void*)&csp};
          hipLaunchCooperativeKernel((const void*)k_lstm2d, dim3(2*C), dim3(512), args, 0, stream);
        }
        if (layer == 1){
          hipLaunchKernelGGL(k_feats_half, dim3(C*T/4), dim3(256), 0, stream,
                             h1s, fcw, fcb, feats, b0, logT, Tm1, sF*T, 0);
          hipLaunchKernelGGL(k_feats_half, dim3(C*T/4), dim3(256), 0, stream,
                             h1s, fcw, fcb, feats, b0, logT, Tm1, sB*T, 1);
        }
      }
    }
  }
  hipLaunchKernelGGL(k_viterbi, dim3(16), dim3(256), 0, stream, feats, trans, (float*)d_out);
}